// Round 8
// baseline (796.501 us; speedup 1.0000x reference)
//
#include <hip/hip_runtime.h>

// PersonaGNN: 2-layer GAT, N=100000, E=600000 (+self loops), dims 128, fp32 io.
//
// R8:
//  - agg reverted to R6 shape (1 node/quad, 16 nodes/block) — R7's 2-node/quad
//    serialized the latency chains and regressed 43->48us.
//  - Launch count 12 -> 8: setup_k = prep_w + zero(deg/partial/counter);
//    scatter fused into the gemm-L1 launch (independent work overlaps);
//    finalize folded into agg-L2 via atomic-counter last-block pattern.
//  - gemm = R7 v5 (LDS-staged fragment-ordered W, ds_read_b128 frags).

#define NEG_SLOPE 0.2f

typedef __attribute__((ext_vector_type(8))) short bf16x8;
typedef __attribute__((ext_vector_type(4))) float f32x4;

__device__ __forceinline__ float leaky(float x) { return x > 0.0f ? x : NEG_SLOPE * x; }

__device__ __forceinline__ unsigned int bf16rne(float f) {
  unsigned int u = __float_as_uint(f);
  return (u + 0x7fffu + ((u >> 16) & 1u)) >> 16;
}
__device__ __forceinline__ unsigned int packbf(float a, float b) {
  return bf16rne(a) | (bf16rne(b) << 16);
}
__device__ __forceinline__ float bf_lo(unsigned int u) { return __uint_as_float(u << 16); }
__device__ __forceinline__ float bf_hi(unsigned int u) { return __uint_as_float(u & 0xffff0000u); }

__device__ __forceinline__ void accum8(float* a, float w, uint4 h) {
  a[0] += w * bf_lo(h.x); a[1] += w * bf_hi(h.x);
  a[2] += w * bf_lo(h.y); a[3] += w * bf_hi(h.y);
  a[4] += w * bf_lo(h.z); a[5] += w * bf_hi(h.z);
  a[6] += w * bf_lo(h.w); a[7] += w * bf_hi(h.w);
}

// ---------------- setup: pack W1/W2 to fragment order + zero scratch ----------------
// blocks 0,1: W pack. blocks 2..: zero deg (N ints), partial (8192 f), counter.
__global__ __launch_bounds__(256) void setup_k(const float* __restrict__ W1,
                                               const float* __restrict__ W2,
                                               unsigned short* __restrict__ Wf1,
                                               unsigned short* __restrict__ Wf2,
                                               int* __restrict__ deg,
                                               float* __restrict__ partial,
                                               unsigned int* __restrict__ counter,
                                               int n, int nzb) {
  const int b = blockIdx.x;
  if (b < 2) {
    const float* W = b ? W2 : W1;
    unsigned short* Wf = b ? Wf2 : Wf1;
    for (int idx = threadIdx.x; idx < 16384; idx += 256) {
      int j = idx & 7;
      int lane = (idx >> 3) & 63;
      int fid = idx >> 9;
      int ct = fid >> 2, ks = fid & 3;
      int q = lane >> 4, l15 = lane & 15;
      Wf[idx] = (unsigned short)bf16rne(W[(ks * 32 + q * 8 + j) * 128 + ct * 16 + l15]);
    }
    return;
  }
  if (b == 2) {
    // zero partial + counter
    for (int i = threadIdx.x; i < 64 * 128; i += 256) partial[i] = 0.f;
    if (threadIdx.x == 0) *counter = 0u;
    return;
  }
  // zero deg: blocks 3..(3+nzb)
  int base = (b - 3) * 1024 + threadIdx.x * 4;
#pragma unroll
  for (int i = 0; i < 4; i++)
    if (base + i < n) deg[base + i] = 0;
}

// ---------------- CSR build ----------------
__global__ void hist_kernel(const int* __restrict__ dst, int* __restrict__ deg, int E) {
  int e = blockIdx.x * 256 + threadIdx.x;
  if (e < E) atomicAdd(&deg[dst[e]], 1);
}

__global__ void scan_a(const int* __restrict__ cnt, int* __restrict__ exc,
                       int* __restrict__ bsum, int n) {
  __shared__ int sh[256];
  int b = blockIdx.x, tid = threadIdx.x;
  int base = b * 1024 + tid * 4;
  int v[4];
#pragma unroll
  for (int i = 0; i < 4; i++) v[i] = (base + i < n) ? cnt[base + i] : 0;
  int tsum = v[0] + v[1] + v[2] + v[3];
  sh[tid] = tsum;
  __syncthreads();
  for (int o = 1; o < 256; o <<= 1) {
    int t = (tid >= o) ? sh[tid - o] : 0;
    __syncthreads();
    sh[tid] += t;
    __syncthreads();
  }
  if (tid == 255) bsum[b] = sh[255];
  int run = sh[tid] - tsum;
#pragma unroll
  for (int i = 0; i < 4; i++) {
    if (base + i < n) exc[base + i] = run;
    run += v[i];
  }
}

__global__ void scan_c2(const int* __restrict__ exc, const int* __restrict__ bsum,
                        int* __restrict__ rowst, int* __restrict__ fill, int n, int E,
                        int nb) {
  __shared__ int red[256];
  int b = blockIdx.x, tid = threadIdx.x;
  red[tid] = (tid < b && tid < nb) ? bsum[tid] : 0;
  __syncthreads();
#pragma unroll
  for (int o = 128; o; o >>= 1) {
    if (tid < o) red[tid] += red[tid + o];
    __syncthreads();
  }
  int off = red[0];
  int base = b * 1024 + tid * 4;
#pragma unroll
  for (int i = 0; i < 4; i++) {
    int idx = base + i;
    if (idx < n) {
      int v = exc[idx] + off;
      rowst[idx] = v;
      fill[idx] = v;
    }
  }
  if (b == 0 && tid == 0) rowst[n] = E;
}

// ------- fused: scatter (blocks < eblocks) || gemm layer-1 (rest) -------
// gemm: Wf staged to LDS once per block; frags via ds_read_b128; 1 tile/wave.
__global__ __launch_bounds__(256) void scatter_gemm1(
    const int* __restrict__ src, const int* __restrict__ dst, int* __restrict__ fill,
    int* __restrict__ esrc, int E, int eblocks,
    const float* __restrict__ Xf, const unsigned short* __restrict__ Wf,
    const float* __restrict__ a_s, const float* __restrict__ a_d,
    unsigned short* __restrict__ H, float* __restrict__ vas,
    float* __restrict__ vad, int n, int nt16) {
  __shared__ unsigned short WL[32 * 512];  // 32 KB

  if (blockIdx.x < eblocks) {
    int e = blockIdx.x * 256 + threadIdx.x;
    if (e < E) {
      int v = dst[e];
      int p = atomicAdd(&fill[v], 1);
      esrc[p] = src[e];
    }
    return;
  }

  const int gbid = blockIdx.x - eblocks;
  const int lane = threadIdx.x & 63;
  const int wv = threadIdx.x >> 6;
  const int l15 = lane & 15;
  const int q = lane >> 4;
  const int t = gbid * 4 + wv;
  const bool wact = t < nt16;
  const int myrow = t * 16 + l15;
  const bool act = wact && (myrow < n);

  // issue X loads before staging so both fly together
  float4 rawf[8];
  if (wact) {
#pragma unroll
    for (int ks = 0; ks < 4; ks++) {
      float4 z = {0.f, 0.f, 0.f, 0.f};
      rawf[2 * ks] = z;
      rawf[2 * ks + 1] = z;
      if (act) {
        rawf[2 * ks] = *(const float4*)&Xf[(size_t)myrow * 128 + ks * 32 + q * 8];
        rawf[2 * ks + 1] = *(const float4*)&Xf[(size_t)myrow * 128 + ks * 32 + q * 8 + 4];
      }
    }
  }
  {
    const uint4* __restrict__ Wg4 = (const uint4*)Wf;
    uint4* WL4 = (uint4*)WL;
#pragma unroll
    for (int j = 0; j < 8; j++) WL4[threadIdx.x + 256 * j] = Wg4[threadIdx.x + 256 * j];
  }
  __syncthreads();
  if (!wact) return;

  bf16x8 xf[4];
#pragma unroll
  for (int ks = 0; ks < 4; ks++) {
    union { bf16x8 v; unsigned int u[4]; } cv;
    cv.u[0] = packbf(rawf[2 * ks].x, rawf[2 * ks].y);
    cv.u[1] = packbf(rawf[2 * ks].z, rawf[2 * ks].w);
    cv.u[2] = packbf(rawf[2 * ks + 1].x, rawf[2 * ks + 1].y);
    cv.u[3] = packbf(rawf[2 * ks + 1].z, rawf[2 * ks + 1].w);
    xf[ks] = cv.v;
  }

  f32x4 acc[8];
#pragma unroll
  for (int ct = 0; ct < 8; ct++) acc[ct] = (f32x4){0.f, 0.f, 0.f, 0.f};
#pragma unroll
  for (int ks = 0; ks < 4; ks++) {
    bf16x8 wf[8];
#pragma unroll
    for (int ct = 0; ct < 8; ct++)
      wf[ct] = *(const bf16x8*)&WL[(((ct << 2) + ks) << 9) + lane * 8];
#pragma unroll
    for (int ct = 0; ct < 8; ct++)
      acc[ct] = __builtin_amdgcn_mfma_f32_16x16x32_bf16(wf[ct], xf[ks], acc[ct], 0, 0, 0);
  }

  float ds = 0.f, dd = 0.f;
#pragma unroll
  for (int ct = 0; ct < 8; ct++) {
    const int c0 = ct * 16 + q * 4;
    float4 as4 = *(const float4*)&a_s[c0];
    float4 ad4 = *(const float4*)&a_d[c0];
    ds += acc[ct][0] * as4.x + acc[ct][1] * as4.y + acc[ct][2] * as4.z + acc[ct][3] * as4.w;
    dd += acc[ct][0] * ad4.x + acc[ct][1] * ad4.y + acc[ct][2] * ad4.z + acc[ct][3] * ad4.w;
    if (act) {
      uint2 o;
      o.x = packbf(acc[ct][0], acc[ct][1]);
      o.y = packbf(acc[ct][2], acc[ct][3]);
      *(uint2*)&H[(size_t)myrow * 128 + c0] = o;
    }
  }
  ds += __shfl_xor(ds, 16, 64);
  ds += __shfl_xor(ds, 32, 64);
  dd += __shfl_xor(dd, 16, 64);
  dd += __shfl_xor(dd, 32, 64);
  if (q == 0 && act) {
    vas[myrow] = ds;
    vad[myrow] = dd;
  }
}

// ------- MFMA GEMM (layer 2, bf16 in): same structure, standalone -------
__global__ __launch_bounds__(256) void gemm_mfma2(const unsigned short* __restrict__ Xh,
                                                  const unsigned short* __restrict__ Wf,
                                                  const float* __restrict__ a_s,
                                                  const float* __restrict__ a_d,
                                                  unsigned short* __restrict__ H,
                                                  float* __restrict__ vas,
                                                  float* __restrict__ vad, int n,
                                                  int nt16) {
  __shared__ unsigned short WL[32 * 512];
  const int lane = threadIdx.x & 63;
  const int wv = threadIdx.x >> 6;
  const int l15 = lane & 15;
  const int q = lane >> 4;
  const int t = blockIdx.x * 4 + wv;
  const bool wact = t < nt16;
  const int myrow = t * 16 + l15;
  const bool act = wact && (myrow < n);

  bf16x8 xf[4];
  if (wact) {
#pragma unroll
    for (int ks = 0; ks < 4; ks++)
      xf[ks] = *(const bf16x8*)&Xh[(size_t)myrow * 128 + ks * 32 + q * 8];  // padded buf
  }
  {
    const uint4* __restrict__ Wg4 = (const uint4*)Wf;
    uint4* WL4 = (uint4*)WL;
#pragma unroll
    for (int j = 0; j < 8; j++) WL4[threadIdx.x + 256 * j] = Wg4[threadIdx.x + 256 * j];
  }
  __syncthreads();
  if (!wact) return;

  f32x4 acc[8];
#pragma unroll
  for (int ct = 0; ct < 8; ct++) acc[ct] = (f32x4){0.f, 0.f, 0.f, 0.f};
#pragma unroll
  for (int ks = 0; ks < 4; ks++) {
    bf16x8 wf[8];
#pragma unroll
    for (int ct = 0; ct < 8; ct++)
      wf[ct] = *(const bf16x8*)&WL[(((ct << 2) + ks) << 9) + lane * 8];
#pragma unroll
    for (int ct = 0; ct < 8; ct++)
      acc[ct] = __builtin_amdgcn_mfma_f32_16x16x32_bf16(wf[ct], xf[ks], acc[ct], 0, 0, 0);
  }

  float ds = 0.f, dd = 0.f;
#pragma unroll
  for (int ct = 0; ct < 8; ct++) {
    const int c0 = ct * 16 + q * 4;
    float4 as4 = *(const float4*)&a_s[c0];
    float4 ad4 = *(const float4*)&a_d[c0];
    ds += acc[ct][0] * as4.x + acc[ct][1] * as4.y + acc[ct][2] * as4.z + acc[ct][3] * as4.w;
    dd += acc[ct][0] * ad4.x + acc[ct][1] * ad4.y + acc[ct][2] * ad4.z + acc[ct][3] * ad4.w;
    if (act) {
      uint2 o;
      o.x = packbf(acc[ct][0], acc[ct][1]);
      o.y = packbf(acc[ct][2], acc[ct][3]);
      *(uint2*)&H[(size_t)myrow * 128 + c0] = o;
    }
  }
  ds += __shfl_xor(ds, 16, 64);
  ds += __shfl_xor(ds, 32, 64);
  dd += __shfl_xor(dd, 16, 64);
  dd += __shfl_xor(dd, 32, 64);
  if (q == 0 && act) {
    vas[myrow] = ds;
    vad[myrow] = dd;
  }
}

// ------------- GAT aggregation (R6 shape): 4 nodes/wave, 16 lanes/node -------------
// LAYER==1: relu + bf16 out. LAYER==2: fused mean + last-block finalize.
template <int LAYER>
__global__ __launch_bounds__(256) void gat_agg2(const unsigned short* __restrict__ H,
                                                const float* __restrict__ vas,
                                                const float* __restrict__ vad,
                                                const int* __restrict__ rowst,
                                                const int* __restrict__ esrc,
                                                const float* __restrict__ bias,
                                                unsigned short* __restrict__ OutBf,
                                                float* __restrict__ partial,
                                                unsigned int* __restrict__ counter,
                                                float* __restrict__ out, int n) {
  const int tid = threadIdx.x;
  const int lane = tid & 63;
  const int wv = tid >> 6;
  const int q = lane >> 4;
  const int l = lane & 15;
  const int node = (blockIdx.x * 4 + wv) * 4 + q;  // 16 nodes per block
  const uint4* __restrict__ H4 = (const uint4*)H;

  float acc[8];
#pragma unroll
  for (int k = 0; k < 8; k++) acc[k] = 0.f;

  if (node < n) {
    const int s = rowst[node];
    const int e = rowst[node + 1];
    const int deg = e - s;
    const float adv = vad[node];
    const float eself = leaky(vas[node] + adv);
    uint4 hs = H4[(size_t)node * 16 + l];
    float wself, dsum;

    if (deg <= 16) {
      int uj = 0;
      float ej = -1e30f;
      const bool a = l < deg;
      if (a) {
        uj = esrc[s + l];
        ej = leaky(vas[uj] + adv);
      }
      float m = fmaxf(eself, ej);
#pragma unroll
      for (int o = 8; o; o >>= 1) m = fmaxf(m, __shfl_xor(m, o, 16));
      float wj = a ? __expf(ej - m) : 0.f;
      wself = __expf(eself - m);
      dsum = wj;
#pragma unroll
      for (int o = 8; o; o >>= 1) dsum += __shfl_xor(dsum, o, 16);
#pragma unroll 1
      for (int t0 = 0; t0 < deg; t0 += 8) {
        const int tb = deg - t0;  // wave-uniform
        uint4 hb[8];
        float wt[8];
#pragma unroll
        for (int i = 0; i < 8; i++) {
          if (i < tb) {
            int ut = __shfl(uj, (lane & 48) + t0 + i, 64);
            wt[i] = __shfl(wj, (lane & 48) + t0 + i, 64);
            hb[i] = H4[(size_t)ut * 16 + l];
          }
        }
#pragma unroll
        for (int i = 0; i < 8; i++)
          if (i < tb) accum8(acc, wt[i], hb[i]);
      }
    } else {
      float m = eself;
      for (int t0 = 0; t0 < deg; t0 += 16) {
        int j = t0 + l;
        if (j < deg) m = fmaxf(m, leaky(vas[esrc[s + j]] + adv));
      }
#pragma unroll
      for (int o = 8; o; o >>= 1) m = fmaxf(m, __shfl_xor(m, o, 16));
      wself = __expf(eself - m);
      float dl = 0.f;
      for (int t0 = 0; t0 < deg; t0 += 16) {
        int j = t0 + l;
        int u2 = 0;
        float w2 = 0.f;
        if (j < deg) {
          u2 = esrc[s + j];
          w2 = __expf(leaky(vas[u2] + adv) - m);
          dl += w2;
        }
        const int cnt = min(16, deg - t0);
        for (int i0 = 0; i0 < cnt; i0 += 8) {
          const int tb = cnt - i0;
          uint4 hb[8];
          float wt[8];
#pragma unroll
          for (int i = 0; i < 8; i++) {
            if (i < tb) {
              int ut = __shfl(u2, (lane & 48) + i0 + i, 64);
              wt[i] = __shfl(w2, (lane & 48) + i0 + i, 64);
              hb[i] = H4[(size_t)ut * 16 + l];
            }
          }
#pragma unroll
          for (int i = 0; i < 8; i++)
            if (i < tb) accum8(acc, wt[i], hb[i]);
        }
      }
      dsum = dl;
#pragma unroll
      for (int o = 8; o; o >>= 1) dsum += __shfl_xor(dsum, o, 16);
    }

    accum8(acc, wself, hs);
    const float inv = 1.0f / (dsum + wself);
    float4 b0 = *(const float4*)&bias[8 * l];
    float4 b1v = *(const float4*)&bias[8 * l + 4];
    acc[0] = acc[0] * inv + b0.x; acc[1] = acc[1] * inv + b0.y;
    acc[2] = acc[2] * inv + b0.z; acc[3] = acc[3] * inv + b0.w;
    acc[4] = acc[4] * inv + b1v.x; acc[5] = acc[5] * inv + b1v.y;
    acc[6] = acc[6] * inv + b1v.z; acc[7] = acc[7] * inv + b1v.w;

    if (LAYER == 1) {
#pragma unroll
      for (int k = 0; k < 8; k++) acc[k] = fmaxf(acc[k], 0.f);
      uint4 o;
      o.x = packbf(acc[0], acc[1]);
      o.y = packbf(acc[2], acc[3]);
      o.z = packbf(acc[4], acc[5]);
      o.w = packbf(acc[6], acc[7]);
      ((uint4*)OutBf)[(size_t)node * 16 + l] = o;
    }
  } else if (LAYER == 2) {
#pragma unroll
    for (int k = 0; k < 8; k++) acc[k] = 0.f;
  }

  if (LAYER == 2) {
#pragma unroll
    for (int k = 0; k < 8; k++) {
      acc[k] += __shfl_xor(acc[k], 16, 64);
      acc[k] += __shfl_xor(acc[k], 32, 64);
    }
    __shared__ float red[4][128];
    __shared__ bool is_last;
    if (q == 0) {
#pragma unroll
      for (int k = 0; k < 8; k++) red[wv][8 * l + k] = acc[k];
    }
    __syncthreads();
    if (tid < 128) {
      float sm = red[0][tid] + red[1][tid] + red[2][tid] + red[3][tid];
      atomicAdd(&partial[(blockIdx.x & 63) * 128 + tid], sm);
    }
    // last-block finalize
    __threadfence();
    if (tid == 0) {
      unsigned int old = atomicAdd(counter, 1u);
      is_last = (old == gridDim.x - 1);
    }
    __syncthreads();
    if (is_last) {
      __threadfence();
      if (tid < 128) {
        float s = 0.f;
#pragma unroll 8
        for (int r = 0; r < 64; r++) s += partial[r * 128 + tid];
        out[tid] = s / (float)n;
      }
    }
  }
}

extern "C" void kernel_launch(void* const* d_in, const int* in_sizes, int n_in,
                              void* d_out, int out_size, void* d_ws, size_t ws_size,
                              hipStream_t stream) {
  const float* x = (const float*)d_in[0];
  const int* ei = (const int*)d_in[1];
  const float* W1 = (const float*)d_in[2];
  const float* a_src1 = (const float*)d_in[3];
  const float* a_dst1 = (const float*)d_in[4];
  const float* b1 = (const float*)d_in[5];
  const float* W2 = (const float*)d_in[6];
  const float* a_src2 = (const float*)d_in[7];
  const float* a_dst2 = (const float*)d_in[8];
  const float* b2 = (const float*)d_in[9];
  float* out = (float*)d_out;

  const int N = in_sizes[0] / 128;
  const int E = in_sizes[1] / 2;
  const int* src = ei;
  const int* dst = ei + E;

  const size_t rowpadded = (size_t)(N + 64) * 128;

  char* p = (char*)d_ws;
  unsigned short* B1h = (unsigned short*)p; p += rowpadded * 2;  // layer-1 agg out (bf16)
  unsigned short* Hh = (unsigned short*)p;  p += rowpadded * 2;  // per-layer GEMM out (bf16)
  float* vas = (float*)p;     p += (size_t)N * 4;
  float* vad = (float*)p;     p += (size_t)N * 4;
  int* deg = (int*)p;         p += (size_t)N * 4;
  int* rowst = (int*)p;       p += (size_t)(N + 1) * 4;
  int* fill = (int*)p;        p += (size_t)N * 4;
  int* esrc = (int*)p;        p += (size_t)E * 4;
  int* exc = (int*)p;         p += (size_t)N * 4;
  int* bsum = (int*)p;        p += 256 * 4;
  float* partial = (float*)p; p += 64 * 128 * 4;
  unsigned int* counter = (unsigned int*)p; p += 64;  // padded
  unsigned short* Wf1 = (unsigned short*)p; p += 16384 * 2;
  unsigned short* Wf2 = (unsigned short*)p; p += 16384 * 2;

  const int nb = (N + 1023) / 1024;  // 98 (<=128 required by scan_c2 reduce)
  const int eblocks = (E + 255) / 256;
  const int nt16 = (N + 15) / 16;
  const int gemmblocks = (nt16 + 3) / 4;  // 1 tile per wave
  const int aggblocks = (N + 15) / 16;    // 16 nodes per 256-thread block

  // 1. setup: W pack + zero deg/partial/counter
  setup_k<<<3 + nb, 256, 0, stream>>>(W1, W2, Wf1, Wf2, deg, partial, counter, N, nb);
  // 2-4. CSR: hist -> scan_a -> scan_c2
  hist_kernel<<<eblocks, 256, 0, stream>>>(dst, deg, E);
  scan_a<<<nb, 256, 0, stream>>>(deg, exc, bsum, N);
  scan_c2<<<nb, 256, 0, stream>>>(exc, bsum, rowst, fill, N, E, nb);
  // 5. scatter || gemm layer-1
  scatter_gemm1<<<eblocks + gemmblocks, 256, 0, stream>>>(
      src, dst, fill, esrc, E, eblocks, x, Wf1, a_src1, a_dst1, Hh, vas, vad, N, nt16);
  // 6. agg layer-1
  gat_agg2<1><<<aggblocks, 256, 0, stream>>>(Hh, vas, vad, rowst, esrc, b1, B1h,
                                             nullptr, nullptr, nullptr, N);
  // 7. gemm layer-2
  gemm_mfma2<<<gemmblocks, 256, 0, stream>>>(B1h, Wf2, a_src2, a_dst2, Hh, vas, vad, N, nt16);
  // 8. agg layer-2 + fused mean + finalize
  gat_agg2<2><<<aggblocks, 256, 0, stream>>>(Hh, vas, vad, rowst, esrc, b2, nullptr,
                                             partial, counter, out, N);
}

// Round 9
// 292.996 us; speedup vs baseline: 2.7185x; 2.7185x over previous
//
#include <hip/hip_runtime.h>

// PersonaGNN: 2-layer GAT, N=100000, E=600000 (+self loops), dims 128, fp32 io.
//
// R9:
//  - REVERTED R8's last-block finalize: per-block __threadfence() on gfx950
//    drains/writes back non-coherent XCD L2s -> agg-L2 took 549us at 2% VALU.
//    Separate finalize_k restored.
//  - gemm v6: W staged to LDS once/block; each wave runs TWO 16-row tiles,
//    software-pipelined (t1's X loads issued before t0's compute) -> halves
//    wave count, hides one load latency per wave. 782 blocks, ~12 waves/CU.
//  - Kept R8 fusions: setup_k (W pack + zeroing), scatter || gemm-L1.

#define NEG_SLOPE 0.2f

typedef __attribute__((ext_vector_type(8))) short bf16x8;
typedef __attribute__((ext_vector_type(4))) float f32x4;

__device__ __forceinline__ float leaky(float x) { return x > 0.0f ? x : NEG_SLOPE * x; }

__device__ __forceinline__ unsigned int bf16rne(float f) {
  unsigned int u = __float_as_uint(f);
  return (u + 0x7fffu + ((u >> 16) & 1u)) >> 16;
}
__device__ __forceinline__ unsigned int packbf(float a, float b) {
  return bf16rne(a) | (bf16rne(b) << 16);
}
__device__ __forceinline__ float bf_lo(unsigned int u) { return __uint_as_float(u << 16); }
__device__ __forceinline__ float bf_hi(unsigned int u) { return __uint_as_float(u & 0xffff0000u); }

__device__ __forceinline__ void accum8(float* a, float w, uint4 h) {
  a[0] += w * bf_lo(h.x); a[1] += w * bf_hi(h.x);
  a[2] += w * bf_lo(h.y); a[3] += w * bf_hi(h.y);
  a[4] += w * bf_lo(h.z); a[5] += w * bf_hi(h.z);
  a[6] += w * bf_lo(h.w); a[7] += w * bf_hi(h.w);
}

// ---------------- setup: pack W1/W2 to fragment order + zero scratch ----------------
__global__ __launch_bounds__(256) void setup_k(const float* __restrict__ W1,
                                               const float* __restrict__ W2,
                                               unsigned short* __restrict__ Wf1,
                                               unsigned short* __restrict__ Wf2,
                                               int* __restrict__ deg,
                                               float* __restrict__ partial,
                                               int n, int nzb) {
  const int b = blockIdx.x;
  if (b < 2) {
    const float* W = b ? W2 : W1;
    unsigned short* Wf = b ? Wf2 : Wf1;
    for (int idx = threadIdx.x; idx < 16384; idx += 256) {
      int j = idx & 7;
      int lane = (idx >> 3) & 63;
      int fid = idx >> 9;
      int ct = fid >> 2, ks = fid & 3;
      int q = lane >> 4, l15 = lane & 15;
      Wf[idx] = (unsigned short)bf16rne(W[(ks * 32 + q * 8 + j) * 128 + ct * 16 + l15]);
    }
    return;
  }
  if (b == 2) {
    for (int i = threadIdx.x; i < 64 * 128; i += 256) partial[i] = 0.f;
    return;
  }
  int base = (b - 3) * 1024 + threadIdx.x * 4;
#pragma unroll
  for (int i = 0; i < 4; i++)
    if (base + i < n) deg[base + i] = 0;
}

// ---------------- CSR build ----------------
__global__ void hist_kernel(const int* __restrict__ dst, int* __restrict__ deg, int E) {
  int e = blockIdx.x * 256 + threadIdx.x;
  if (e < E) atomicAdd(&deg[dst[e]], 1);
}

__global__ void scan_a(const int* __restrict__ cnt, int* __restrict__ exc,
                       int* __restrict__ bsum, int n) {
  __shared__ int sh[256];
  int b = blockIdx.x, tid = threadIdx.x;
  int base = b * 1024 + tid * 4;
  int v[4];
#pragma unroll
  for (int i = 0; i < 4; i++) v[i] = (base + i < n) ? cnt[base + i] : 0;
  int tsum = v[0] + v[1] + v[2] + v[3];
  sh[tid] = tsum;
  __syncthreads();
  for (int o = 1; o < 256; o <<= 1) {
    int t = (tid >= o) ? sh[tid - o] : 0;
    __syncthreads();
    sh[tid] += t;
    __syncthreads();
  }
  if (tid == 255) bsum[b] = sh[255];
  int run = sh[tid] - tsum;
#pragma unroll
  for (int i = 0; i < 4; i++) {
    if (base + i < n) exc[base + i] = run;
    run += v[i];
  }
}

__global__ void scan_c2(const int* __restrict__ exc, const int* __restrict__ bsum,
                        int* __restrict__ rowst, int* __restrict__ fill, int n, int E,
                        int nb) {
  __shared__ int red[256];
  int b = blockIdx.x, tid = threadIdx.x;
  red[tid] = (tid < b && tid < nb) ? bsum[tid] : 0;
  __syncthreads();
#pragma unroll
  for (int o = 128; o; o >>= 1) {
    if (tid < o) red[tid] += red[tid + o];
    __syncthreads();
  }
  int off = red[0];
  int base = b * 1024 + tid * 4;
#pragma unroll
  for (int i = 0; i < 4; i++) {
    int idx = base + i;
    if (idx < n) {
      int v = exc[idx] + off;
      rowst[idx] = v;
      fill[idx] = v;
    }
  }
  if (b == 0 && tid == 0) rowst[n] = E;
}

// ---------------- shared gemm tile pieces ----------------
__device__ __forceinline__ void cvt_f32(const float4* raw, bf16x8* xf) {
#pragma unroll
  for (int ks = 0; ks < 4; ks++) {
    union { bf16x8 v; unsigned int u[4]; } cv;
    cv.u[0] = packbf(raw[2 * ks].x, raw[2 * ks].y);
    cv.u[1] = packbf(raw[2 * ks].z, raw[2 * ks].w);
    cv.u[2] = packbf(raw[2 * ks + 1].x, raw[2 * ks + 1].y);
    cv.u[3] = packbf(raw[2 * ks + 1].z, raw[2 * ks + 1].w);
    xf[ks] = cv.v;
  }
}

__device__ __forceinline__ void mfma_tile(const unsigned short* WL, const bf16x8* xf,
                                          const float* __restrict__ a_s,
                                          const float* __restrict__ a_d,
                                          unsigned short* __restrict__ H,
                                          float* __restrict__ vas,
                                          float* __restrict__ vad, int myrow, bool act,
                                          int lane, int q) {
  f32x4 acc[8];
#pragma unroll
  for (int ct = 0; ct < 8; ct++) acc[ct] = (f32x4){0.f, 0.f, 0.f, 0.f};
#pragma unroll
  for (int ks = 0; ks < 4; ks++) {
    bf16x8 wf[8];
#pragma unroll
    for (int ct = 0; ct < 8; ct++)
      wf[ct] = *(const bf16x8*)&WL[(((ct << 2) + ks) << 9) + lane * 8];
#pragma unroll
    for (int ct = 0; ct < 8; ct++)
      acc[ct] = __builtin_amdgcn_mfma_f32_16x16x32_bf16(wf[ct], xf[ks], acc[ct], 0, 0, 0);
  }
  float ds = 0.f, dd = 0.f;
#pragma unroll
  for (int ct = 0; ct < 8; ct++) {
    const int c0 = ct * 16 + q * 4;
    float4 as4 = *(const float4*)&a_s[c0];
    float4 ad4 = *(const float4*)&a_d[c0];
    ds += acc[ct][0] * as4.x + acc[ct][1] * as4.y + acc[ct][2] * as4.z + acc[ct][3] * as4.w;
    dd += acc[ct][0] * ad4.x + acc[ct][1] * ad4.y + acc[ct][2] * ad4.z + acc[ct][3] * ad4.w;
    if (act) {
      uint2 o;
      o.x = packbf(acc[ct][0], acc[ct][1]);
      o.y = packbf(acc[ct][2], acc[ct][3]);
      *(uint2*)&H[(size_t)myrow * 128 + c0] = o;
    }
  }
  ds += __shfl_xor(ds, 16, 64);
  ds += __shfl_xor(ds, 32, 64);
  dd += __shfl_xor(dd, 16, 64);
  dd += __shfl_xor(dd, 32, 64);
  if (q == 0 && act) {
    vas[myrow] = ds;
    vad[myrow] = dd;
  }
}

// ------- fused: scatter (blocks < eblocks) || gemm layer-1 (2 tiles/wave) -------
__global__ __launch_bounds__(256) void scatter_gemm1(
    const int* __restrict__ src, const int* __restrict__ dst, int* __restrict__ fill,
    int* __restrict__ esrc, int E, int eblocks,
    const float* __restrict__ Xf, const unsigned short* __restrict__ Wf,
    const float* __restrict__ a_s, const float* __restrict__ a_d,
    unsigned short* __restrict__ H, float* __restrict__ vas,
    float* __restrict__ vad, int n, int nt16, int ngemm) {
  __shared__ unsigned short WL[32 * 512];  // 32 KB

  if (blockIdx.x < eblocks) {
    int e = blockIdx.x * 256 + threadIdx.x;
    if (e < E) {
      int v = dst[e];
      int p = atomicAdd(&fill[v], 1);
      esrc[p] = src[e];
    }
    return;
  }

  const int gbid = blockIdx.x - eblocks;
  const int lane = threadIdx.x & 63;
  const int wv = threadIdx.x >> 6;
  const int l15 = lane & 15;
  const int q = lane >> 4;
  const int t0 = gbid * 4 + wv;
  const int t1 = t0 + ngemm * 4;
  const int r0 = t0 * 16 + l15;
  const int r1 = t1 * 16 + l15;
  const bool wact0 = t0 < nt16;
  const bool wact1 = t1 < nt16;
  const bool act0 = wact0 && (r0 < n);
  const bool act1 = wact1 && (r1 < n);

  // issue t0's X loads before staging so both fly together
  float4 raw0[8];
  if (wact0) {
#pragma unroll
    for (int ks = 0; ks < 4; ks++) {
      float4 z = {0.f, 0.f, 0.f, 0.f};
      raw0[2 * ks] = z;
      raw0[2 * ks + 1] = z;
      if (act0) {
        raw0[2 * ks] = *(const float4*)&Xf[(size_t)r0 * 128 + ks * 32 + q * 8];
        raw0[2 * ks + 1] = *(const float4*)&Xf[(size_t)r0 * 128 + ks * 32 + q * 8 + 4];
      }
    }
  }
  {
    const uint4* __restrict__ Wg4 = (const uint4*)Wf;
    uint4* WL4 = (uint4*)WL;
#pragma unroll
    for (int j = 0; j < 8; j++) WL4[threadIdx.x + 256 * j] = Wg4[threadIdx.x + 256 * j];
  }
  __syncthreads();
  if (!wact0) return;

  // prefetch t1's X loads, then compute t0 (hides t1's latency)
  float4 raw1[8];
  if (wact1) {
#pragma unroll
    for (int ks = 0; ks < 4; ks++) {
      float4 z = {0.f, 0.f, 0.f, 0.f};
      raw1[2 * ks] = z;
      raw1[2 * ks + 1] = z;
      if (act1) {
        raw1[2 * ks] = *(const float4*)&Xf[(size_t)r1 * 128 + ks * 32 + q * 8];
        raw1[2 * ks + 1] = *(const float4*)&Xf[(size_t)r1 * 128 + ks * 32 + q * 8 + 4];
      }
    }
  }

  bf16x8 xf[4];
  cvt_f32(raw0, xf);
  mfma_tile(WL, xf, a_s, a_d, H, vas, vad, r0, act0, lane, q);
  if (wact1) {
    cvt_f32(raw1, xf);
    mfma_tile(WL, xf, a_s, a_d, H, vas, vad, r1, act1, lane, q);
  }
}

// ------- MFMA GEMM layer-2 (bf16 in), 2 tiles/wave pipelined -------
__global__ __launch_bounds__(256) void gemm_mfma2(const unsigned short* __restrict__ Xh,
                                                  const unsigned short* __restrict__ Wf,
                                                  const float* __restrict__ a_s,
                                                  const float* __restrict__ a_d,
                                                  unsigned short* __restrict__ H,
                                                  float* __restrict__ vas,
                                                  float* __restrict__ vad, int n,
                                                  int nt16, int ngemm) {
  __shared__ unsigned short WL[32 * 512];
  const int lane = threadIdx.x & 63;
  const int wv = threadIdx.x >> 6;
  const int l15 = lane & 15;
  const int q = lane >> 4;
  const int t0 = blockIdx.x * 4 + wv;
  const int t1 = t0 + ngemm * 4;
  const int r0 = t0 * 16 + l15;
  const int r1 = t1 * 16 + l15;
  const bool wact0 = t0 < nt16;
  const bool wact1 = t1 < nt16;
  const bool act0 = wact0 && (r0 < n);
  const bool act1 = wact1 && (r1 < n);

  bf16x8 xf0[4], xf1[4];
  if (wact0) {
#pragma unroll
    for (int ks = 0; ks < 4; ks++)
      xf0[ks] = *(const bf16x8*)&Xh[(size_t)r0 * 128 + ks * 32 + q * 8];  // padded buf
  }
  {
    const uint4* __restrict__ Wg4 = (const uint4*)Wf;
    uint4* WL4 = (uint4*)WL;
#pragma unroll
    for (int j = 0; j < 8; j++) WL4[threadIdx.x + 256 * j] = Wg4[threadIdx.x + 256 * j];
  }
  __syncthreads();
  if (!wact0) return;

  if (wact1) {
#pragma unroll
    for (int ks = 0; ks < 4; ks++)
      xf1[ks] = *(const bf16x8*)&Xh[(size_t)r1 * 128 + ks * 32 + q * 8];
  }

  mfma_tile(WL, xf0, a_s, a_d, H, vas, vad, r0, act0, lane, q);
  if (wact1) mfma_tile(WL, xf1, a_s, a_d, H, vas, vad, r1, act1, lane, q);
}

// ------------- GAT aggregation (R6 shape): 4 nodes/wave, 16 lanes/node -------------
// LAYER==1: relu + bf16 out. LAYER==2: fused mean into partial[64][128].
template <int LAYER>
__global__ __launch_bounds__(256) void gat_agg2(const unsigned short* __restrict__ H,
                                                const float* __restrict__ vas,
                                                const float* __restrict__ vad,
                                                const int* __restrict__ rowst,
                                                const int* __restrict__ esrc,
                                                const float* __restrict__ bias,
                                                unsigned short* __restrict__ OutBf,
                                                float* __restrict__ partial, int n) {
  const int tid = threadIdx.x;
  const int lane = tid & 63;
  const int wv = tid >> 6;
  const int q = lane >> 4;
  const int l = lane & 15;
  const int node = (blockIdx.x * 4 + wv) * 4 + q;  // 16 nodes per block
  const uint4* __restrict__ H4 = (const uint4*)H;

  float acc[8];
#pragma unroll
  for (int k = 0; k < 8; k++) acc[k] = 0.f;

  if (node < n) {
    const int s = rowst[node];
    const int e = rowst[node + 1];
    const int deg = e - s;
    const float adv = vad[node];
    const float eself = leaky(vas[node] + adv);
    uint4 hs = H4[(size_t)node * 16 + l];
    float wself, dsum;

    if (deg <= 16) {
      int uj = 0;
      float ej = -1e30f;
      const bool a = l < deg;
      if (a) {
        uj = esrc[s + l];
        ej = leaky(vas[uj] + adv);
      }
      float m = fmaxf(eself, ej);
#pragma unroll
      for (int o = 8; o; o >>= 1) m = fmaxf(m, __shfl_xor(m, o, 16));
      float wj = a ? __expf(ej - m) : 0.f;
      wself = __expf(eself - m);
      dsum = wj;
#pragma unroll
      for (int o = 8; o; o >>= 1) dsum += __shfl_xor(dsum, o, 16);
#pragma unroll 1
      for (int t0 = 0; t0 < deg; t0 += 8) {
        const int tb = deg - t0;  // wave-uniform
        uint4 hb[8];
        float wt[8];
#pragma unroll
        for (int i = 0; i < 8; i++) {
          if (i < tb) {
            int ut = __shfl(uj, (lane & 48) + t0 + i, 64);
            wt[i] = __shfl(wj, (lane & 48) + t0 + i, 64);
            hb[i] = H4[(size_t)ut * 16 + l];
          }
        }
#pragma unroll
        for (int i = 0; i < 8; i++)
          if (i < tb) accum8(acc, wt[i], hb[i]);
      }
    } else {
      float m = eself;
      for (int t0 = 0; t0 < deg; t0 += 16) {
        int j = t0 + l;
        if (j < deg) m = fmaxf(m, leaky(vas[esrc[s + j]] + adv));
      }
#pragma unroll
      for (int o = 8; o; o >>= 1) m = fmaxf(m, __shfl_xor(m, o, 16));
      wself = __expf(eself - m);
      float dl = 0.f;
      for (int t0 = 0; t0 < deg; t0 += 16) {
        int j = t0 + l;
        int u2 = 0;
        float w2 = 0.f;
        if (j < deg) {
          u2 = esrc[s + j];
          w2 = __expf(leaky(vas[u2] + adv) - m);
          dl += w2;
        }
        const int cnt = min(16, deg - t0);
        for (int i0 = 0; i0 < cnt; i0 += 8) {
          const int tb = cnt - i0;
          uint4 hb[8];
          float wt[8];
#pragma unroll
          for (int i = 0; i < 8; i++) {
            if (i < tb) {
              int ut = __shfl(u2, (lane & 48) + i0 + i, 64);
              wt[i] = __shfl(w2, (lane & 48) + i0 + i, 64);
              hb[i] = H4[(size_t)ut * 16 + l];
            }
          }
#pragma unroll
          for (int i = 0; i < 8; i++)
            if (i < tb) accum8(acc, wt[i], hb[i]);
        }
      }
      dsum = dl;
#pragma unroll
      for (int o = 8; o; o >>= 1) dsum += __shfl_xor(dsum, o, 16);
    }

    accum8(acc, wself, hs);
    const float inv = 1.0f / (dsum + wself);
    float4 b0 = *(const float4*)&bias[8 * l];
    float4 b1v = *(const float4*)&bias[8 * l + 4];
    acc[0] = acc[0] * inv + b0.x; acc[1] = acc[1] * inv + b0.y;
    acc[2] = acc[2] * inv + b0.z; acc[3] = acc[3] * inv + b0.w;
    acc[4] = acc[4] * inv + b1v.x; acc[5] = acc[5] * inv + b1v.y;
    acc[6] = acc[6] * inv + b1v.z; acc[7] = acc[7] * inv + b1v.w;

    if (LAYER == 1) {
#pragma unroll
      for (int k = 0; k < 8; k++) acc[k] = fmaxf(acc[k], 0.f);
      uint4 o;
      o.x = packbf(acc[0], acc[1]);
      o.y = packbf(acc[2], acc[3]);
      o.z = packbf(acc[4], acc[5]);
      o.w = packbf(acc[6], acc[7]);
      ((uint4*)OutBf)[(size_t)node * 16 + l] = o;
    }
  }

  if (LAYER == 2) {
#pragma unroll
    for (int k = 0; k < 8; k++) {
      acc[k] += __shfl_xor(acc[k], 16, 64);
      acc[k] += __shfl_xor(acc[k], 32, 64);
    }
    __shared__ float red[4][128];
    if (q == 0) {
#pragma unroll
      for (int k = 0; k < 8; k++) red[wv][8 * l + k] = acc[k];
    }
    __syncthreads();
    if (tid < 128) {
      float sm = red[0][tid] + red[1][tid] + red[2][tid] + red[3][tid];
      atomicAdd(&partial[(blockIdx.x & 63) * 128 + tid], sm);
    }
  }
}

// ---------------- finalize: out = sum(partial)/N ----------------
__global__ void finalize_k(const float* __restrict__ partial, float* __restrict__ out,
                           float invn) {
  int c = threadIdx.x;  // 128
  float s = 0.f;
#pragma unroll 8
  for (int r = 0; r < 64; r++) s += partial[r * 128 + c];
  out[c] = s * invn;
}

extern "C" void kernel_launch(void* const* d_in, const int* in_sizes, int n_in,
                              void* d_out, int out_size, void* d_ws, size_t ws_size,
                              hipStream_t stream) {
  const float* x = (const float*)d_in[0];
  const int* ei = (const int*)d_in[1];
  const float* W1 = (const float*)d_in[2];
  const float* a_src1 = (const float*)d_in[3];
  const float* a_dst1 = (const float*)d_in[4];
  const float* b1 = (const float*)d_in[5];
  const float* W2 = (const float*)d_in[6];
  const float* a_src2 = (const float*)d_in[7];
  const float* a_dst2 = (const float*)d_in[8];
  const float* b2 = (const float*)d_in[9];
  float* out = (float*)d_out;

  const int N = in_sizes[0] / 128;
  const int E = in_sizes[1] / 2;
  const int* src = ei;
  const int* dst = ei + E;

  const size_t rowpadded = (size_t)(N + 256) * 128;

  char* p = (char*)d_ws;
  unsigned short* B1h = (unsigned short*)p; p += rowpadded * 2;  // layer-1 agg out (bf16)
  unsigned short* Hh = (unsigned short*)p;  p += rowpadded * 2;  // per-layer GEMM out (bf16)
  float* vas = (float*)p;     p += (size_t)N * 4;
  float* vad = (float*)p;     p += (size_t)N * 4;
  int* deg = (int*)p;         p += (size_t)N * 4;
  int* rowst = (int*)p;       p += (size_t)(N + 1) * 4;
  int* fill = (int*)p;        p += (size_t)N * 4;
  int* esrc = (int*)p;        p += (size_t)E * 4;
  int* exc = (int*)p;         p += (size_t)N * 4;
  int* bsum = (int*)p;        p += 256 * 4;
  float* partial = (float*)p; p += 64 * 128 * 4;
  unsigned short* Wf1 = (unsigned short*)p; p += 16384 * 2;
  unsigned short* Wf2 = (unsigned short*)p; p += 16384 * 2;

  const int nb = (N + 1023) / 1024;  // 98 (<=128 required by scan_c2 reduce)
  const int eblocks = (E + 255) / 256;
  const int nt16 = (N + 15) / 16;
  const int ngemm = (nt16 + 7) / 8;     // 2 tiles per wave
  const int aggblocks = (N + 15) / 16;  // 16 nodes per 256-thread block

  // 1. setup: W pack + zero deg/partial
  setup_k<<<3 + nb, 256, 0, stream>>>(W1, W2, Wf1, Wf2, deg, partial, N, nb);
  // 2-4. CSR: hist -> scan_a -> scan_c2
  hist_kernel<<<eblocks, 256, 0, stream>>>(dst, deg, E);
  scan_a<<<nb, 256, 0, stream>>>(deg, exc, bsum, N);
  scan_c2<<<nb, 256, 0, stream>>>(exc, bsum, rowst, fill, N, E, nb);
  // 5. scatter || gemm layer-1
  scatter_gemm1<<<eblocks + ngemm, 256, 0, stream>>>(
      src, dst, fill, esrc, E, eblocks, x, Wf1, a_src1, a_dst1, Hh, vas, vad, N, nt16, ngemm);
  // 6. agg layer-1
  gat_agg2<1><<<aggblocks, 256, 0, stream>>>(Hh, vas, vad, rowst, esrc, b1, B1h, nullptr, N);
  // 7. gemm layer-2
  gemm_mfma2<<<ngemm, 256, 0, stream>>>(B1h, Wf2, a_src2, a_dst2, Hh, vas, vad, N, nt16, ngemm);
  // 8. agg layer-2 + fused mean partials
  gat_agg2<2><<<aggblocks, 256, 0, stream>>>(Hh, vas, vad, rowst, esrc, b2, nullptr, partial, N);
  // 9. finalize
  finalize_k<<<1, 128, 0, stream>>>(partial, out, 1.0f / (float)N);
}

// Round 10
// 288.953 us; speedup vs baseline: 2.7565x; 1.0140x over previous
//
#include <hip/hip_runtime.h>

// PersonaGNN: 2-layer GAT, N=100000, E=600000 (+self loops), dims 128, fp32 io.
//
// R10:
//  - Un-fused scatter (R9's fusion gave scatter blocks the gemm's 32KB-LDS/
//    160-VGPR footprint -> 3 blocks/CU for latency-bound atomics; 69us).
//  - gemm2 FUSED into agg1: each agg1 block owns 16 consecutive nodes = one
//    16-row MFMA tile. relu'd bf16 rows -> 4KB swizzled LDS A-tile -> 4 waves
//    split 8 column-tiles (W frags from L2-hot Wf2) -> write H2 + vas2/vad2.
//    Deletes gemm2 dispatch + 51MB B1h write/read. Numerics identical.
//  - gemm1 standalone (LDS-staged W, 2 tiles/wave pipelined).

#define NEG_SLOPE 0.2f

typedef __attribute__((ext_vector_type(8))) short bf16x8;
typedef __attribute__((ext_vector_type(4))) float f32x4;

__device__ __forceinline__ float leaky(float x) { return x > 0.0f ? x : NEG_SLOPE * x; }

__device__ __forceinline__ unsigned int bf16rne(float f) {
  unsigned int u = __float_as_uint(f);
  return (u + 0x7fffu + ((u >> 16) & 1u)) >> 16;
}
__device__ __forceinline__ unsigned int packbf(float a, float b) {
  return bf16rne(a) | (bf16rne(b) << 16);
}
__device__ __forceinline__ float bf_lo(unsigned int u) { return __uint_as_float(u << 16); }
__device__ __forceinline__ float bf_hi(unsigned int u) { return __uint_as_float(u & 0xffff0000u); }

__device__ __forceinline__ void accum8(float* a, float w, uint4 h) {
  a[0] += w * bf_lo(h.x); a[1] += w * bf_hi(h.x);
  a[2] += w * bf_lo(h.y); a[3] += w * bf_hi(h.y);
  a[4] += w * bf_lo(h.z); a[5] += w * bf_hi(h.z);
  a[6] += w * bf_lo(h.w); a[7] += w * bf_hi(h.w);
}

// ---------------- setup: pack W1/W2 to fragment order + zero scratch ----------------
__global__ __launch_bounds__(256) void setup_k(const float* __restrict__ W1,
                                               const float* __restrict__ W2,
                                               unsigned short* __restrict__ Wf1,
                                               unsigned short* __restrict__ Wf2,
                                               int* __restrict__ deg,
                                               float* __restrict__ partial,
                                               int n, int nzb) {
  const int b = blockIdx.x;
  if (b < 2) {
    const float* W = b ? W2 : W1;
    unsigned short* Wf = b ? Wf2 : Wf1;
    for (int idx = threadIdx.x; idx < 16384; idx += 256) {
      int j = idx & 7;
      int lane = (idx >> 3) & 63;
      int fid = idx >> 9;
      int ct = fid >> 2, ks = fid & 3;
      int q = lane >> 4, l15 = lane & 15;
      Wf[idx] = (unsigned short)bf16rne(W[(ks * 32 + q * 8 + j) * 128 + ct * 16 + l15]);
    }
    return;
  }
  if (b == 2) {
    for (int i = threadIdx.x; i < 64 * 128; i += 256) partial[i] = 0.f;
    return;
  }
  int base = (b - 3) * 1024 + threadIdx.x * 4;
#pragma unroll
  for (int i = 0; i < 4; i++)
    if (base + i < n) deg[base + i] = 0;
}

// ---------------- CSR build ----------------
__global__ void hist_kernel(const int* __restrict__ dst, int* __restrict__ deg, int E) {
  int e = blockIdx.x * 256 + threadIdx.x;
  if (e < E) atomicAdd(&deg[dst[e]], 1);
}

__global__ void scan_a(const int* __restrict__ cnt, int* __restrict__ exc,
                       int* __restrict__ bsum, int n) {
  __shared__ int sh[256];
  int b = blockIdx.x, tid = threadIdx.x;
  int base = b * 1024 + tid * 4;
  int v[4];
#pragma unroll
  for (int i = 0; i < 4; i++) v[i] = (base + i < n) ? cnt[base + i] : 0;
  int tsum = v[0] + v[1] + v[2] + v[3];
  sh[tid] = tsum;
  __syncthreads();
  for (int o = 1; o < 256; o <<= 1) {
    int t = (tid >= o) ? sh[tid - o] : 0;
    __syncthreads();
    sh[tid] += t;
    __syncthreads();
  }
  if (tid == 255) bsum[b] = sh[255];
  int run = sh[tid] - tsum;
#pragma unroll
  for (int i = 0; i < 4; i++) {
    if (base + i < n) exc[base + i] = run;
    run += v[i];
  }
}

__global__ void scan_c2(const int* __restrict__ exc, const int* __restrict__ bsum,
                        int* __restrict__ rowst, int* __restrict__ fill, int n, int E,
                        int nb) {
  __shared__ int red[256];
  int b = blockIdx.x, tid = threadIdx.x;
  red[tid] = (tid < b && tid < nb) ? bsum[tid] : 0;
  __syncthreads();
#pragma unroll
  for (int o = 128; o; o >>= 1) {
    if (tid < o) red[tid] += red[tid + o];
    __syncthreads();
  }
  int off = red[0];
  int base = b * 1024 + tid * 4;
#pragma unroll
  for (int i = 0; i < 4; i++) {
    int idx = base + i;
    if (idx < n) {
      int v = exc[idx] + off;
      rowst[idx] = v;
      fill[idx] = v;
    }
  }
  if (b == 0 && tid == 0) rowst[n] = E;
}

__global__ void scatter_kernel(const int* __restrict__ src, const int* __restrict__ dst,
                               int* __restrict__ fill, int* __restrict__ esrc, int E) {
  int e = blockIdx.x * 256 + threadIdx.x;
  if (e < E) {
    int v = dst[e];
    int p = atomicAdd(&fill[v], 1);
    esrc[p] = src[e];
  }
}

// ---------------- shared gemm tile pieces ----------------
__device__ __forceinline__ void cvt_f32(const float4* raw, bf16x8* xf) {
#pragma unroll
  for (int ks = 0; ks < 4; ks++) {
    union { bf16x8 v; unsigned int u[4]; } cv;
    cv.u[0] = packbf(raw[2 * ks].x, raw[2 * ks].y);
    cv.u[1] = packbf(raw[2 * ks].z, raw[2 * ks].w);
    cv.u[2] = packbf(raw[2 * ks + 1].x, raw[2 * ks + 1].y);
    cv.u[3] = packbf(raw[2 * ks + 1].z, raw[2 * ks + 1].w);
    xf[ks] = cv.v;
  }
}

__device__ __forceinline__ void mfma_tile(const unsigned short* WL, const bf16x8* xf,
                                          const float* __restrict__ a_s,
                                          const float* __restrict__ a_d,
                                          unsigned short* __restrict__ H,
                                          float* __restrict__ vas,
                                          float* __restrict__ vad, int myrow, bool act,
                                          int lane, int q) {
  f32x4 acc[8];
#pragma unroll
  for (int ct = 0; ct < 8; ct++) acc[ct] = (f32x4){0.f, 0.f, 0.f, 0.f};
#pragma unroll
  for (int ks = 0; ks < 4; ks++) {
    bf16x8 wf[8];
#pragma unroll
    for (int ct = 0; ct < 8; ct++)
      wf[ct] = *(const bf16x8*)&WL[(((ct << 2) + ks) << 9) + lane * 8];
#pragma unroll
    for (int ct = 0; ct < 8; ct++)
      acc[ct] = __builtin_amdgcn_mfma_f32_16x16x32_bf16(wf[ct], xf[ks], acc[ct], 0, 0, 0);
  }
  float ds = 0.f, dd = 0.f;
#pragma unroll
  for (int ct = 0; ct < 8; ct++) {
    const int c0 = ct * 16 + q * 4;
    float4 as4 = *(const float4*)&a_s[c0];
    float4 ad4 = *(const float4*)&a_d[c0];
    ds += acc[ct][0] * as4.x + acc[ct][1] * as4.y + acc[ct][2] * as4.z + acc[ct][3] * as4.w;
    dd += acc[ct][0] * ad4.x + acc[ct][1] * ad4.y + acc[ct][2] * ad4.z + acc[ct][3] * ad4.w;
    if (act) {
      uint2 o;
      o.x = packbf(acc[ct][0], acc[ct][1]);
      o.y = packbf(acc[ct][2], acc[ct][3]);
      *(uint2*)&H[(size_t)myrow * 128 + c0] = o;
    }
  }
  ds += __shfl_xor(ds, 16, 64);
  ds += __shfl_xor(ds, 32, 64);
  dd += __shfl_xor(dd, 16, 64);
  dd += __shfl_xor(dd, 32, 64);
  if (q == 0 && act) {
    vas[myrow] = ds;
    vad[myrow] = dd;
  }
}

// ------- GEMM layer-1 (fp32 x in), LDS-staged W, 2 tiles/wave pipelined -------
__global__ __launch_bounds__(256) void gemm_mfma1(const float* __restrict__ Xf,
                                                  const unsigned short* __restrict__ Wf,
                                                  const float* __restrict__ a_s,
                                                  const float* __restrict__ a_d,
                                                  unsigned short* __restrict__ H,
                                                  float* __restrict__ vas,
                                                  float* __restrict__ vad, int n,
                                                  int nt16, int ngemm) {
  __shared__ unsigned short WL[32 * 512];  // 32 KB
  const int lane = threadIdx.x & 63;
  const int wv = threadIdx.x >> 6;
  const int l15 = lane & 15;
  const int q = lane >> 4;
  const int t0 = blockIdx.x * 4 + wv;
  const int t1 = t0 + ngemm * 4;
  const int r0 = t0 * 16 + l15;
  const int r1 = t1 * 16 + l15;
  const bool wact0 = t0 < nt16;
  const bool wact1 = t1 < nt16;
  const bool act0 = wact0 && (r0 < n);
  const bool act1 = wact1 && (r1 < n);

  float4 raw0[8];
  if (wact0) {
#pragma unroll
    for (int ks = 0; ks < 4; ks++) {
      float4 z = {0.f, 0.f, 0.f, 0.f};
      raw0[2 * ks] = z;
      raw0[2 * ks + 1] = z;
      if (act0) {
        raw0[2 * ks] = *(const float4*)&Xf[(size_t)r0 * 128 + ks * 32 + q * 8];
        raw0[2 * ks + 1] = *(const float4*)&Xf[(size_t)r0 * 128 + ks * 32 + q * 8 + 4];
      }
    }
  }
  {
    const uint4* __restrict__ Wg4 = (const uint4*)Wf;
    uint4* WL4 = (uint4*)WL;
#pragma unroll
    for (int j = 0; j < 8; j++) WL4[threadIdx.x + 256 * j] = Wg4[threadIdx.x + 256 * j];
  }
  __syncthreads();
  if (!wact0) return;

  float4 raw1[8];
  if (wact1) {
#pragma unroll
    for (int ks = 0; ks < 4; ks++) {
      float4 z = {0.f, 0.f, 0.f, 0.f};
      raw1[2 * ks] = z;
      raw1[2 * ks + 1] = z;
      if (act1) {
        raw1[2 * ks] = *(const float4*)&Xf[(size_t)r1 * 128 + ks * 32 + q * 8];
        raw1[2 * ks + 1] = *(const float4*)&Xf[(size_t)r1 * 128 + ks * 32 + q * 8 + 4];
      }
    }
  }

  bf16x8 xf[4];
  cvt_f32(raw0, xf);
  mfma_tile(WL, xf, a_s, a_d, H, vas, vad, r0, act0, lane, q);
  if (wact1) {
    cvt_f32(raw1, xf);
    mfma_tile(WL, xf, a_s, a_d, H, vas, vad, r1, act1, lane, q);
  }
}

// ------------- FUSED agg layer-1 + gemm layer-2 -------------
// Block = 16 consecutive nodes. agg1 (relu+bias) -> swizzled LDS A-tile ->
// 4 waves split 8 column-tiles of the 16x128x128 MFMA -> write HB + vas2/vad2.
__global__ __launch_bounds__(256) void agg1_gemm2(
    const unsigned short* __restrict__ HA, const float* __restrict__ vas1,
    const float* __restrict__ vad1, const int* __restrict__ rowst,
    const int* __restrict__ esrc, const float* __restrict__ b1,
    const unsigned short* __restrict__ Wf2, const float* __restrict__ a_s2,
    const float* __restrict__ a_d2, unsigned short* __restrict__ HB,
    float* __restrict__ vas2, float* __restrict__ vad2, int n) {
  __shared__ unsigned short Atile[16 * 128];  // 4KB, 16B chunks XOR-swizzled by row&7
  __shared__ float sdot[2][4][16];
  const int tid = threadIdx.x;
  const int lane = tid & 63;
  const int wv = tid >> 6;
  const int q = lane >> 4;
  const int l = lane & 15;
  const int row = wv * 4 + q;             // 0..15 within tile
  const int node = blockIdx.x * 16 + row; // consecutive nodes per block
  const uint4* __restrict__ H4 = (const uint4*)HA;

  float acc[8];
#pragma unroll
  for (int k = 0; k < 8; k++) acc[k] = 0.f;

  uint4 o = {0u, 0u, 0u, 0u};
  if (node < n) {
    const int s = rowst[node];
    const int e = rowst[node + 1];
    const int deg = e - s;
    const float adv = vad1[node];
    const float eself = leaky(vas1[node] + adv);
    uint4 hs = H4[(size_t)node * 16 + l];
    float wself, dsum;

    if (deg <= 16) {
      int uj = 0;
      float ej = -1e30f;
      const bool a = l < deg;
      if (a) {
        uj = esrc[s + l];
        ej = leaky(vas1[uj] + adv);
      }
      float m = fmaxf(eself, ej);
#pragma unroll
      for (int oo = 8; oo; oo >>= 1) m = fmaxf(m, __shfl_xor(m, oo, 16));
      float wj = a ? __expf(ej - m) : 0.f;
      wself = __expf(eself - m);
      dsum = wj;
#pragma unroll
      for (int oo = 8; oo; oo >>= 1) dsum += __shfl_xor(dsum, oo, 16);
#pragma unroll 1
      for (int t0 = 0; t0 < deg; t0 += 8) {
        const int tb = deg - t0;
        uint4 hb[8];
        float wt[8];
#pragma unroll
        for (int i = 0; i < 8; i++) {
          if (i < tb) {
            int ut = __shfl(uj, (lane & 48) + t0 + i, 64);
            wt[i] = __shfl(wj, (lane & 48) + t0 + i, 64);
            hb[i] = H4[(size_t)ut * 16 + l];
          }
        }
#pragma unroll
        for (int i = 0; i < 8; i++)
          if (i < tb) accum8(acc, wt[i], hb[i]);
      }
    } else {
      float m = eself;
      for (int t0 = 0; t0 < deg; t0 += 16) {
        int j = t0 + l;
        if (j < deg) m = fmaxf(m, leaky(vas1[esrc[s + j]] + adv));
      }
#pragma unroll
      for (int oo = 8; oo; oo >>= 1) m = fmaxf(m, __shfl_xor(m, oo, 16));
      wself = __expf(eself - m);
      float dl = 0.f;
      for (int t0 = 0; t0 < deg; t0 += 16) {
        int j = t0 + l;
        int u2 = 0;
        float w2 = 0.f;
        if (j < deg) {
          u2 = esrc[s + j];
          w2 = __expf(leaky(vas1[u2] + adv) - m);
          dl += w2;
        }
        const int cnt = min(16, deg - t0);
        for (int i0 = 0; i0 < cnt; i0 += 8) {
          const int tb = cnt - i0;
          uint4 hb[8];
          float wt[8];
#pragma unroll
          for (int i = 0; i < 8; i++) {
            if (i < tb) {
              int ut = __shfl(u2, (lane & 48) + i0 + i, 64);
              wt[i] = __shfl(w2, (lane & 48) + i0 + i, 64);
              hb[i] = H4[(size_t)ut * 16 + l];
            }
          }
#pragma unroll
          for (int i = 0; i < 8; i++)
            if (i < tb) accum8(acc, wt[i], hb[i]);
        }
      }
      dsum = dl;
#pragma unroll
      for (int oo = 8; oo; oo >>= 1) dsum += __shfl_xor(dsum, oo, 16);
    }

    accum8(acc, wself, hs);
    const float inv = 1.0f / (dsum + wself);
    float4 b0 = *(const float4*)&b1[8 * l];
    float4 b1v = *(const float4*)&b1[8 * l + 4];
    acc[0] = fmaxf(acc[0] * inv + b0.x, 0.f);
    acc[1] = fmaxf(acc[1] * inv + b0.y, 0.f);
    acc[2] = fmaxf(acc[2] * inv + b0.z, 0.f);
    acc[3] = fmaxf(acc[3] * inv + b0.w, 0.f);
    acc[4] = fmaxf(acc[4] * inv + b1v.x, 0.f);
    acc[5] = fmaxf(acc[5] * inv + b1v.y, 0.f);
    acc[6] = fmaxf(acc[6] * inv + b1v.z, 0.f);
    acc[7] = fmaxf(acc[7] * inv + b1v.w, 0.f);
    o.x = packbf(acc[0], acc[1]);
    o.y = packbf(acc[2], acc[3]);
    o.z = packbf(acc[4], acc[5]);
    o.w = packbf(acc[6], acc[7]);
  }
  // store row to swizzled A-tile: lane l holds 16B chunk index l
  *(uint4*)&Atile[row * 128 + ((l ^ (row & 7)) << 3)] = o;
  __syncthreads();

  // ---- gemm: A-frags from LDS (lane l = row), W-frags from L2-hot Wf2 ----
  bf16x8 xf[4];
#pragma unroll
  for (int ks = 0; ks < 4; ks++)
    xf[ks] = *(const bf16x8*)&Atile[l * 128 + ((((ks << 2) + q) ^ (l & 7)) << 3)];

  const int ct0 = 2 * wv, ct1 = 2 * wv + 1;
  f32x4 accA = {0.f, 0.f, 0.f, 0.f}, accB = {0.f, 0.f, 0.f, 0.f};
#pragma unroll
  for (int ks = 0; ks < 4; ks++) {
    bf16x8 w0 = *(const bf16x8*)&Wf2[(((ct0 << 2) + ks) << 9) + lane * 8];
    bf16x8 w1 = *(const bf16x8*)&Wf2[(((ct1 << 2) + ks) << 9) + lane * 8];
    accA = __builtin_amdgcn_mfma_f32_16x16x32_bf16(w0, xf[ks], accA, 0, 0, 0);
    accB = __builtin_amdgcn_mfma_f32_16x16x32_bf16(w1, xf[ks], accB, 0, 0, 0);
  }

  const int myrow = blockIdx.x * 16 + l;
  const bool ract = myrow < n;
  float ds = 0.f, dd = 0.f;
  {
    const int c0 = ct0 * 16 + q * 4;
    float4 as4 = *(const float4*)&a_s2[c0];
    float4 ad4 = *(const float4*)&a_d2[c0];
    ds += accA[0] * as4.x + accA[1] * as4.y + accA[2] * as4.z + accA[3] * as4.w;
    dd += accA[0] * ad4.x + accA[1] * ad4.y + accA[2] * ad4.z + accA[3] * ad4.w;
    if (ract) {
      uint2 ov;
      ov.x = packbf(accA[0], accA[1]);
      ov.y = packbf(accA[2], accA[3]);
      *(uint2*)&HB[(size_t)myrow * 128 + c0] = ov;
    }
  }
  {
    const int c0 = ct1 * 16 + q * 4;
    float4 as4 = *(const float4*)&a_s2[c0];
    float4 ad4 = *(const float4*)&a_d2[c0];
    ds += accB[0] * as4.x + accB[1] * as4.y + accB[2] * as4.z + accB[3] * as4.w;
    dd += accB[0] * ad4.x + accB[1] * ad4.y + accB[2] * ad4.z + accB[3] * ad4.w;
    if (ract) {
      uint2 ov;
      ov.x = packbf(accB[0], accB[1]);
      ov.y = packbf(accB[2], accB[3]);
      *(uint2*)&HB[(size_t)myrow * 128 + c0] = ov;
    }
  }
  ds += __shfl_xor(ds, 16, 64);
  ds += __shfl_xor(ds, 32, 64);
  dd += __shfl_xor(dd, 16, 64);
  dd += __shfl_xor(dd, 32, 64);
  if (q == 0) {
    sdot[0][wv][l] = ds;
    sdot[1][wv][l] = dd;
  }
  __syncthreads();
  if (tid < 16) {
    int nn = blockIdx.x * 16 + tid;
    if (nn < n) {
      vas2[nn] = sdot[0][0][tid] + sdot[0][1][tid] + sdot[0][2][tid] + sdot[0][3][tid];
      vad2[nn] = sdot[1][0][tid] + sdot[1][1][tid] + sdot[1][2][tid] + sdot[1][3][tid];
    }
  }
}

// ------------- GAT aggregation layer-2 + fused mean partials -------------
__global__ __launch_bounds__(256) void gat_agg_l2(const unsigned short* __restrict__ H,
                                                  const float* __restrict__ vas,
                                                  const float* __restrict__ vad,
                                                  const int* __restrict__ rowst,
                                                  const int* __restrict__ esrc,
                                                  const float* __restrict__ bias,
                                                  float* __restrict__ partial, int n) {
  const int tid = threadIdx.x;
  const int lane = tid & 63;
  const int wv = tid >> 6;
  const int q = lane >> 4;
  const int l = lane & 15;
  const int node = (blockIdx.x * 4 + wv) * 4 + q;
  const uint4* __restrict__ H4 = (const uint4*)H;

  float acc[8];
#pragma unroll
  for (int k = 0; k < 8; k++) acc[k] = 0.f;

  if (node < n) {
    const int s = rowst[node];
    const int e = rowst[node + 1];
    const int deg = e - s;
    const float adv = vad[node];
    const float eself = leaky(vas[node] + adv);
    uint4 hs = H4[(size_t)node * 16 + l];
    float wself, dsum;

    if (deg <= 16) {
      int uj = 0;
      float ej = -1e30f;
      const bool a = l < deg;
      if (a) {
        uj = esrc[s + l];
        ej = leaky(vas[uj] + adv);
      }
      float m = fmaxf(eself, ej);
#pragma unroll
      for (int o = 8; o; o >>= 1) m = fmaxf(m, __shfl_xor(m, o, 16));
      float wj = a ? __expf(ej - m) : 0.f;
      wself = __expf(eself - m);
      dsum = wj;
#pragma unroll
      for (int o = 8; o; o >>= 1) dsum += __shfl_xor(dsum, o, 16);
#pragma unroll 1
      for (int t0 = 0; t0 < deg; t0 += 8) {
        const int tb = deg - t0;
        uint4 hb[8];
        float wt[8];
#pragma unroll
        for (int i = 0; i < 8; i++) {
          if (i < tb) {
            int ut = __shfl(uj, (lane & 48) + t0 + i, 64);
            wt[i] = __shfl(wj, (lane & 48) + t0 + i, 64);
            hb[i] = H4[(size_t)ut * 16 + l];
          }
        }
#pragma unroll
        for (int i = 0; i < 8; i++)
          if (i < tb) accum8(acc, wt[i], hb[i]);
      }
    } else {
      float m = eself;
      for (int t0 = 0; t0 < deg; t0 += 16) {
        int j = t0 + l;
        if (j < deg) m = fmaxf(m, leaky(vas[esrc[s + j]] + adv));
      }
#pragma unroll
      for (int o = 8; o; o >>= 1) m = fmaxf(m, __shfl_xor(m, o, 16));
      wself = __expf(eself - m);
      float dl = 0.f;
      for (int t0 = 0; t0 < deg; t0 += 16) {
        int j = t0 + l;
        int u2 = 0;
        float w2 = 0.f;
        if (j < deg) {
          u2 = esrc[s + j];
          w2 = __expf(leaky(vas[u2] + adv) - m);
          dl += w2;
        }
        const int cnt = min(16, deg - t0);
        for (int i0 = 0; i0 < cnt; i0 += 8) {
          const int tb = cnt - i0;
          uint4 hb[8];
          float wt[8];
#pragma unroll
          for (int i = 0; i < 8; i++) {
            if (i < tb) {
              int ut = __shfl(u2, (lane & 48) + i0 + i, 64);
              wt[i] = __shfl(w2, (lane & 48) + i0 + i, 64);
              hb[i] = H4[(size_t)ut * 16 + l];
            }
          }
#pragma unroll
          for (int i = 0; i < 8; i++)
            if (i < tb) accum8(acc, wt[i], hb[i]);
        }
      }
      dsum = dl;
#pragma unroll
      for (int o = 8; o; o >>= 1) dsum += __shfl_xor(dsum, o, 16);
    }

    accum8(acc, wself, hs);
    const float inv = 1.0f / (dsum + wself);
    float4 b0 = *(const float4*)&bias[8 * l];
    float4 b1v = *(const float4*)&bias[8 * l + 4];
    acc[0] = acc[0] * inv + b0.x; acc[1] = acc[1] * inv + b0.y;
    acc[2] = acc[2] * inv + b0.z; acc[3] = acc[3] * inv + b0.w;
    acc[4] = acc[4] * inv + b1v.x; acc[5] = acc[5] * inv + b1v.y;
    acc[6] = acc[6] * inv + b1v.z; acc[7] = acc[7] * inv + b1v.w;
  }

#pragma unroll
  for (int k = 0; k < 8; k++) {
    acc[k] += __shfl_xor(acc[k], 16, 64);
    acc[k] += __shfl_xor(acc[k], 32, 64);
  }
  __shared__ float red[4][128];
  if (q == 0) {
#pragma unroll
    for (int k = 0; k < 8; k++) red[wv][8 * l + k] = acc[k];
  }
  __syncthreads();
  if (tid < 128) {
    float sm = red[0][tid] + red[1][tid] + red[2][tid] + red[3][tid];
    atomicAdd(&partial[(blockIdx.x & 63) * 128 + tid], sm);
  }
}

// ---------------- finalize: out = sum(partial)/N ----------------
__global__ void finalize_k(const float* __restrict__ partial, float* __restrict__ out,
                           float invn) {
  int c = threadIdx.x;  // 128
  float s = 0.f;
#pragma unroll 8
  for (int r = 0; r < 64; r++) s += partial[r * 128 + c];
  out[c] = s * invn;
}

extern "C" void kernel_launch(void* const* d_in, const int* in_sizes, int n_in,
                              void* d_out, int out_size, void* d_ws, size_t ws_size,
                              hipStream_t stream) {
  const float* x = (const float*)d_in[0];
  const int* ei = (const int*)d_in[1];
  const float* W1 = (const float*)d_in[2];
  const float* a_src1 = (const float*)d_in[3];
  const float* a_dst1 = (const float*)d_in[4];
  const float* b1 = (const float*)d_in[5];
  const float* W2 = (const float*)d_in[6];
  const float* a_src2 = (const float*)d_in[7];
  const float* a_dst2 = (const float*)d_in[8];
  const float* b2 = (const float*)d_in[9];
  float* out = (float*)d_out;

  const int N = in_sizes[0] / 128;
  const int E = in_sizes[1] / 2;
  const int* src = ei;
  const int* dst = ei + E;

  const size_t rowpadded = (size_t)(N + 256) * 128;

  char* p = (char*)d_ws;
  unsigned short* HA = (unsigned short*)p; p += rowpadded * 2;  // gemm1 out (bf16)
  unsigned short* HB = (unsigned short*)p; p += rowpadded * 2;  // fused agg1+gemm2 out (bf16)
  float* vas1 = (float*)p;    p += (size_t)N * 4;
  float* vad1 = (float*)p;    p += (size_t)N * 4;
  float* vas2 = (float*)p;    p += (size_t)N * 4;
  float* vad2 = (float*)p;    p += (size_t)N * 4;
  int* deg = (int*)p;         p += (size_t)N * 4;
  int* rowst = (int*)p;       p += (size_t)(N + 1) * 4;
  int* fill = (int*)p;        p += (size_t)N * 4;
  int* esrc = (int*)p;        p += (size_t)E * 4;
  int* exc = (int*)p;         p += (size_t)N * 4;
  int* bsum = (int*)p;        p += 256 * 4;
  float* partial = (float*)p; p += 64 * 128 * 4;
  unsigned short* Wf1 = (unsigned short*)p; p += 16384 * 2;
  unsigned short* Wf2 = (unsigned short*)p; p += 16384 * 2;

  const int nb = (N + 1023) / 1024;  // 98 (<=128 required by scan_c2 reduce)
  const int eblocks = (E + 255) / 256;
  const int nt16 = (N + 15) / 16;
  const int ngemm = (nt16 + 7) / 8;     // 2 tiles per wave
  const int aggblocks = (N + 15) / 16;  // 16 nodes per 256-thread block

  // 1. setup: W pack + zero deg/partial
  setup_k<<<3 + nb, 256, 0, stream>>>(W1, W2, Wf1, Wf2, deg, partial, N, nb);
  // 2-5. CSR
  hist_kernel<<<eblocks, 256, 0, stream>>>(dst, deg, E);
  scan_a<<<nb, 256, 0, stream>>>(deg, exc, bsum, N);
  scan_c2<<<nb, 256, 0, stream>>>(exc, bsum, rowst, fill, N, E, nb);
  scatter_kernel<<<eblocks, 256, 0, stream>>>(src, dst, fill, esrc, E);
  // 6. gemm layer-1
  gemm_mfma1<<<ngemm, 256, 0, stream>>>(x, Wf1, a_src1, a_dst1, HA, vas1, vad1, N, nt16, ngemm);
  // 7. fused agg layer-1 + gemm layer-2
  agg1_gemm2<<<aggblocks, 256, 0, stream>>>(HA, vas1, vad1, rowst, esrc, b1, Wf2,
                                            a_src2, a_dst2, HB, vas2, vad2, N);
  // 8. agg layer-2 + mean partials
  gat_agg_l2<<<aggblocks, 256, 0, stream>>>(HB, vas2, vad2, rowst, esrc, b2, partial, N);
  // 9. finalize
  finalize_k<<<1, 128, 0, stream>>>(partial, out, 1.0f / (float)N);
}